// Round 2
// baseline (2300.941 us; speedup 1.0000x reference)
//
#include <hip/hip_runtime.h>
#include <hip/hip_bf16.h>

#define N_NODES   500000
#define HIDDEN    256
#define NCLASS    104
#define NGRAPH    2048
#define NTILE     31250      // N_NODES / 16 rows per wave-iteration
#define WG_STRIDE 520        // 512 + 8 pad (bf16 elems) -> 2-way LDS conflicts max
#define WT_STRIDE 264        // 256 + 8

typedef __attribute__((ext_vector_type(8))) __bf16 bf16x8;
typedef __attribute__((ext_vector_type(8))) unsigned short ushort8;
typedef __attribute__((ext_vector_type(4))) float floatx4;

__device__ __forceinline__ unsigned short f2bf(float f) {
    unsigned u = __float_as_uint(f);
    u += 0x7fffu + ((u >> 16) & 1u);     // round-to-nearest-even
    return (unsigned short)(u >> 16);
}

// ---------------------------------------------------------------------------
// Kernel 0: build bf16 transposed weight buffers in workspace.
//   WgT: [NCLASS][512]   WtT: [NCLASS][256]   (no pad; pad added at LDS fill)
// ---------------------------------------------------------------------------
__global__ void prep_kernel(const float* __restrict__ Wg, const float* __restrict__ Wt,
                            unsigned short* __restrict__ WgT, unsigned short* __restrict__ WtT) {
    int id = blockIdx.x * 256 + threadIdx.x;
    if (id < NCLASS * 512) {
        int c = id >> 9, k = id & 511;
        WgT[id] = f2bf(Wg[k * NCLASS + c]);
    } else {
        int id2 = id - NCLASS * 512;   // < NCLASS*256
        int c = id2 >> 8, k = id2 & 255;
        WtT[id2] = f2bf(Wt[k * NCLASS + c]);
    }
}

// ---------------------------------------------------------------------------
// Kernel 1: gated nodewise readout + segment-sum scatter.
// B-stationary in LDS (written once, one barrier at start); each wave streams
// its own 16 rows global->reg in A-fragment order. NO per-iteration barrier,
// so no vmcnt(0) drain: 8 waves/CU keep ~256 KB in flight continuously.
// ---------------------------------------------------------------------------
__global__ __launch_bounds__(512, 2)
void node_kernel(const float* __restrict__ init_s, const float* __restrict__ fin_s,
                 const int* __restrict__ gl, const float* __restrict__ bg,
                 const float* __restrict__ bt,
                 const unsigned short* __restrict__ WgT,   // [NCLASS][512] bf16
                 const unsigned short* __restrict__ WtT,   // [NCLASS][256] bf16
                 float* __restrict__ readout)              // [NGRAPH][NCLASS]
{
    __shared__ unsigned short Bg_lds[NCLASS * WG_STRIDE];  // 108,160 B
    __shared__ unsigned short Bt_lds[NCLASS * WT_STRIDE];  //  54,912 B  (tot 163,072)

    const int tid  = threadIdx.x;
    const int lane = tid & 63;
    const int w    = tid >> 6;            // wave 0..7
    const int l15  = lane & 15;
    const int quad = lane >> 4;

    // ---- cooperative LDS fill of weights (bank-padded rows) ----
    for (int i = tid; i < NCLASS * 512 / 8; i += 512) {
        const int c = (i * 8) >> 9, k = (i * 8) & 511;
        *reinterpret_cast<ushort8*>(&Bg_lds[c * WG_STRIDE + k]) =
            *reinterpret_cast<const ushort8*>(&WgT[c * 512 + k]);
    }
    for (int i = tid; i < NCLASS * 256 / 8; i += 512) {
        const int c = (i * 8) >> 8, k = (i * 8) & 255;
        *reinterpret_cast<ushort8*>(&Bt_lds[c * WT_STRIDE + k]) =
            *reinterpret_cast<const ushort8*>(&WtT[c * 256 + k]);
    }

    // ---- per-lane bias values for each of the 7 column tiles ----
    float bgv[7], btv[7];
#pragma unroll
    for (int ct = 0; ct < 7; ++ct) {
        int c = ct * 16 + l15; if (c > NCLASS - 1) c = NCLASS - 1;
        bgv[ct] = bg[c]; btv[ct] = bt[c];
    }

    __syncthreads();   // the ONLY barrier

    const int wid = blockIdx.x * 8 + w;

    for (int t = wid; t < NTILE; t += 2048) {
        // ---- stream own 16 rows: lane (l15,quad) loads row t*16+l15,
        //      k = s*32 + quad*8 .. +8  (A-fragment order), fp32 ----
        const int row = t * 16 + l15;
        const float* pi = init_s + (size_t)row * HIDDEN + quad * 8;
        const float* pf = fin_s  + (size_t)row * HIDDEN + quad * 8;
        float4 v[16][2];
#pragma unroll
        for (int s = 0; s < 8; ++s) {
            v[s][0]     = *reinterpret_cast<const float4*>(pi + s * 32);
            v[s][1]     = *reinterpret_cast<const float4*>(pi + s * 32 + 4);
            v[s + 8][0] = *reinterpret_cast<const float4*>(pf + s * 32);
            v[s + 8][1] = *reinterpret_cast<const float4*>(pf + s * 32 + 4);
        }
        bf16x8 a[16];
#pragma unroll
        for (int s = 0; s < 16; ++s) {
            ushort8 u;
            u[0] = f2bf(v[s][0].x); u[1] = f2bf(v[s][0].y);
            u[2] = f2bf(v[s][0].z); u[3] = f2bf(v[s][0].w);
            u[4] = f2bf(v[s][1].x); u[5] = f2bf(v[s][1].y);
            u[6] = f2bf(v[s][1].z); u[7] = f2bf(v[s][1].w);
            a[s] = __builtin_bit_cast(bf16x8, u);
        }

        const int gfirst = gl[t * 16];
        const int glast  = gl[t * 16 + 15];

#pragma unroll
        for (int ct = 0; ct < 7; ++ct) {
            int cb = ct * 16 + l15; if (cb > NCLASS - 1) cb = NCLASS - 1;  // clamp pad cols
            const unsigned short* bgp = &Bg_lds[cb * WG_STRIDE + quad * 8];
            const unsigned short* btp = &Bt_lds[cb * WT_STRIDE + quad * 8];
            floatx4 accg = {0.f, 0.f, 0.f, 0.f};
            floatx4 acct = {0.f, 0.f, 0.f, 0.f};
#pragma unroll
            for (int s = 0; s < 16; ++s) {
                bf16x8 bfrag = *reinterpret_cast<const bf16x8*>(bgp + s * 32);
                accg = __builtin_amdgcn_mfma_f32_16x16x32_bf16(a[s], bfrag, accg, 0, 0, 0);
            }
#pragma unroll
            for (int s = 0; s < 8; ++s) {
                bf16x8 bfrag = *reinterpret_cast<const bf16x8*>(btp + s * 32);
                acct = __builtin_amdgcn_mfma_f32_16x16x32_bf16(a[s + 8], bfrag, acct, 0, 0, 0);
            }
            // ---- epilogue: sigmoid gate, scale, segment-sum scatter ----
            float vals[4];
#pragma unroll
            for (int j = 0; j < 4; ++j) {
                const float sg = 1.f / (1.f + __expf(-(accg[j] + bgv[ct])));
                vals[j] = sg * (acct[j] + btv[ct]);
            }
            const int col = ct * 16 + l15;
            if (gfirst == glast) {      // sorted -> whole 16-row tile is one graph
                float vsum = vals[0] + vals[1] + vals[2] + vals[3];
                vsum += __shfl_xor(vsum, 16, 64);
                vsum += __shfl_xor(vsum, 32, 64);
                if (quad == 0 && col < NCLASS)
                    atomicAdd(&readout[gfirst * NCLASS + col], vsum);
            } else {                    // boundary tile (~6.5%): per-row atomics
                if (col < NCLASS) {
#pragma unroll
                    for (int j = 0; j < 4; ++j) {
                        const int g = gl[t * 16 + quad * 4 + j];
                        atomicAdd(&readout[g * NCLASS + col], vals[j]);
                    }
                }
            }
        }
    }
}

// ---------------------------------------------------------------------------
// Kernel 2: BatchNorm (eval) + feed_forward MLP. 8 graphs per block.
// ---------------------------------------------------------------------------
__global__ __launch_bounds__(128)
void mlp_kernel(const float* __restrict__ readout, const float* __restrict__ aux,
                const float* __restrict__ gamma, const float* __restrict__ beta,
                const float* __restrict__ mean, const float* __restrict__ var,
                const float* __restrict__ W1, const float* __restrict__ b1,
                const float* __restrict__ W2, const float* __restrict__ b2,
                float* __restrict__ out)
{
    __shared__ float xs[8][112];
    __shared__ float hs[8][128];
    const int g0 = blockIdx.x * 8;
    const int tid = threadIdx.x;

    for (int v = tid; v < 8 * 106; v += 128) {
        const int r = v / 106, i = v - r * 106;
        const float raw = (i < NCLASS) ? readout[(g0 + r) * NCLASS + i]
                                       : aux[(g0 + r) * 2 + (i - NCLASS)];
        xs[r][i] = (raw - mean[i]) * rsqrtf(var[i] + 1e-5f) * gamma[i] + beta[i];
    }
    __syncthreads();
    {
        const int j = tid;   // 0..127
        float acc[8];
#pragma unroll
        for (int r = 0; r < 8; ++r) acc[r] = b1[j];
        for (int i = 0; i < 106; ++i) {
            const float ww = W1[i * 128 + j];
#pragma unroll
            for (int r = 0; r < 8; ++r) acc[r] += xs[r][i] * ww;
        }
#pragma unroll
        for (int r = 0; r < 8; ++r) hs[r][j] = fmaxf(acc[r], 0.f);
    }
    __syncthreads();
    if (tid < NCLASS) {
        float acc[8];
#pragma unroll
        for (int r = 0; r < 8; ++r) acc[r] = b2[tid];
        for (int j = 0; j < 128; ++j) {
            const float ww = W2[j * NCLASS + tid];
#pragma unroll
            for (int r = 0; r < 8; ++r) acc[r] += hs[r][j] * ww;
        }
#pragma unroll
        for (int r = 0; r < 8; ++r) out[(g0 + r) * NCLASS + tid] = acc[r];
    }
}

// ---------------------------------------------------------------------------
extern "C" void kernel_launch(void* const* d_in, const int* in_sizes, int n_in,
                              void* d_out, int out_size, void* d_ws, size_t ws_size,
                              hipStream_t stream) {
    const float* init_s = (const float*)d_in[0];
    const float* fin_s  = (const float*)d_in[1];
    const float* aux    = (const float*)d_in[2];
    const int*   gl     = (const int*)d_in[3];
    // d_in[4] = num_graphs (2048, hardcoded)
    const float* Wg = (const float*)d_in[5];
    const float* bg = (const float*)d_in[6];
    const float* Wt = (const float*)d_in[7];
    const float* bt = (const float*)d_in[8];
    const float* bn_gamma = (const float*)d_in[9];
    const float* bn_beta  = (const float*)d_in[10];
    const float* bn_mean  = (const float*)d_in[11];
    const float* bn_var   = (const float*)d_in[12];
    const float* W1 = (const float*)d_in[13];
    const float* b1 = (const float*)d_in[14];
    const float* W2 = (const float*)d_in[15];
    const float* b2 = (const float*)d_in[16];
    float* out = (float*)d_out;

    char* ws = (char*)d_ws;
    float* readout      = (float*)ws;                               // 2048*104*4 = 851,968 B
    unsigned short* WgT = (unsigned short*)(ws + 851968);           // 104*512*2 = 106,496 B
    unsigned short* WtT = (unsigned short*)(ws + 851968 + 106496);  // 104*256*2 =  53,248 B

    hipMemsetAsync(readout, 0, NGRAPH * NCLASS * sizeof(float), stream);
    prep_kernel<<<312, 256, 0, stream>>>(Wg, Wt, WgT, WtT);
    node_kernel<<<256, 512, 0, stream>>>(init_s, fin_s, gl, bg, bt, WgT, WtT, readout);
    mlp_kernel<<<NGRAPH / 8, 128, 0, stream>>>(readout, aux, bn_gamma, bn_beta,
                                               bn_mean, bn_var, W1, b1, W2, b2, out);
}